// Round 5
// baseline (2354.597 us; speedup 1.0000x reference)
//
#include <hip/hip_runtime.h>

// RandomMFGL: out[o][g] = (1/4) * sum_n [ (A[n] @ x) @ W[n] + b[n] ]
// A: [4][4096][16384] fp32 = 1.07 GB streamed once -> HBM-bound, floor ~175us.
//
// R5 design (post-mortems R2/R3/R4: A-operand delivery is everything):
//  - 4 lanes per row (p=lane&3 owns 16B of each 64B step), 16 rows/wave ->
//    every A-load inst covers 16 dense 64B lines, 1 KB unique, zero dup.
//  - Ping-pong A batches with the step loop FULLY UNROLLED (compile-time
//    buffer parity -> no v_mov rotation, no per-step vmcnt(0)); a whole
//    compute body (256 FMA + 64 ds) sits between batch issue and use.
//  - x pre-transposed to xT[16][N_IN]; block stages [16][512] = 32 KB to LDS
//    once, then 4 row-passes (256 rows) amortize it. Compute x reads are
//    ds_read_b128 (fixed f, 4 consecutive i): 4 addrs x 16-way broadcast,
//    conflict-free by construction.
//  - Per 1 KB A per wave: 1 VMEM + 16 ds + 64 FMA -> VALU ~32%, LDS ~12%,
//    HBM saturated. Split-K=32 partials, shfl-reduce over the 4 p-lanes.

#define N_ENS 4
#define N_OUT 4096
#define N_IN  16384
#define ROWS  (N_ENS * N_OUT)      // 16384 rows (row = n*4096 + o)
#define GSPLIT 32                  // split-K factor
#define ICHUNK (N_IN / GSPLIT)     // 512 i per block
#define NPASS 4                    // row-groups of 64 rows per block
#define NS    8                    // steps per pass; step = 64 i (16 i/row-lane-quad x ... 1 KB/wave)

// ------------- kernel 0: transpose x [16384][16] -> xT [16][16384] -------------
__global__ __launch_bounds__(256) void k_transpose(const float* __restrict__ x,
                                                   float* __restrict__ xT) {
    int idx = blockIdx.x * 256 + threadIdx.x;   // 0 .. 262143
    int i = idx >> 4;
    int f = idx & 15;
    xT[(size_t)f * N_IN + i] = x[idx];
}

// ------------- kernel 1: hp[split][row][f] = sum_{i in chunk} A[row][i] * x[i][f] -------------
__global__ __launch_bounds__(256, 4) void k_main(const float* __restrict__ A,
                                                 const float* __restrict__ xT,
                                                 float* __restrict__ hp) {
    __shared__ float xs[16 * ICHUNK];            // 32 KB: xs[f][i'] = xT[f][i0+i']

    const int split  = blockIdx.x & (GSPLIT - 1);
    const int rowblk = blockIdx.x >> 5;          // 0..63 (256 rows each)
    const int tid = threadIdx.x;
    const int i0  = split * ICHUNK;

    // ---- stage xT chunk [16][512] into LDS: coalesced global, contiguous LDS ----
#pragma unroll
    for (int j = 0; j < 8; ++j) {
        int k  = tid + 256 * j;                  // float4 id, 2048 total
        int f  = k >> 7;                         // 128 float4 per f-row
        int iw = k & 127;
        float4 v = *(const float4*)(xT + (size_t)f * N_IN + i0 + iw * 4);
        *(float4*)&xs[f * ICHUNK + iw * 4] = v;
    }
    __syncthreads();

    const int wave = tid >> 6;
    const int lane = tid & 63;
    const int r    = lane >> 2;                  // 16 rows per wave
    const int p    = lane & 3;                   // 16B quad within row's 64B step
    const int rowbase = rowblk * 256 + wave * 16 + r;   // + pass*64

    float acc[16];
    float4 ab[2][4];

    // batch (pn, sn) = 4 float4: A[rowbase+pn*64][i0 + sn*64 + p*4 + j*16 ...]
    auto pref = [&](float4* buf, int pn, int sn) {
        const float* ap = A + (size_t)(rowbase + pn * 64) * N_IN + i0 + sn * 64 + (p << 2);
#pragma unroll
        for (int j = 0; j < 4; ++j)
            buf[j] = *(const float4*)(ap + j * 16);
    };
    auto compute = [&](const float4* buf, int s) {
#pragma unroll
        for (int j = 0; j < 4; ++j) {
            const float4 av = buf[j];
            const int xw = s * 64 + j * 16 + (p << 2);
#pragma unroll
            for (int f = 0; f < 16; ++f) {
                float4 xv = *(const float4*)&xs[f * ICHUNK + xw];  // broadcast b128
                acc[f] = fmaf(av.x, xv.x, acc[f]);
                acc[f] = fmaf(av.y, xv.y, acc[f]);
                acc[f] = fmaf(av.z, xv.z, acc[f]);
                acc[f] = fmaf(av.w, xv.w, acc[f]);
            }
        }
    };

    pref(ab[0], 0, 0);
    for (int pass = 0; pass < NPASS; ++pass) {
#pragma unroll
        for (int f = 0; f < 16; ++f) acc[f] = 0.0f;

#pragma unroll
        for (int sh = 0; sh < NS / 2; ++sh) {
            pref(ab[1], pass, 2 * sh + 1);
            compute(ab[0], 2 * sh);
            if (sh < NS / 2 - 1) {
                pref(ab[0], pass, 2 * sh + 2);
            } else {
                int pn = (pass + 1 < NPASS) ? pass + 1 : pass;  // clamped (harmless reload)
                pref(ab[0], pn, 0);
            }
            compute(ab[1], 2 * sh + 1);
        }

        // reduce over the 4 p-lanes sharing each row (butterfly)
#pragma unroll
        for (int f = 0; f < 16; ++f) {
            acc[f] += __shfl_xor(acc[f], 1, 64);
            acc[f] += __shfl_xor(acc[f], 2, 64);
        }
        float4 v;
        if      (p == 0) v = make_float4(acc[0],  acc[1],  acc[2],  acc[3]);
        else if (p == 1) v = make_float4(acc[4],  acc[5],  acc[6],  acc[7]);
        else if (p == 2) v = make_float4(acc[8],  acc[9],  acc[10], acc[11]);
        else             v = make_float4(acc[12], acc[13], acc[14], acc[15]);
        int row = rowbase + pass * 64;
        // wave writes 16 rows x 64 B contiguous -> dense 1 KB segments
        *(float4*)(hp + (((size_t)split * ROWS + row) << 4) + (p << 2)) = v;
    }
}

// ------------- kernel 2: h[row][f] = sum_split hp[split][row][f] (float4) -------------
__global__ __launch_bounds__(256) void k_hsum(const float4* __restrict__ hp4,
                                              float4* __restrict__ h4) {
    int t = blockIdx.x * 256 + threadIdx.x;      // 0 .. 65535 float4s
    float4 s = make_float4(0.f, 0.f, 0.f, 0.f);
#pragma unroll
    for (int sp = 0; sp < GSPLIT; ++sp) {
        float4 v = hp4[(size_t)sp * (ROWS * 4) + t];
        s.x += v.x; s.y += v.y; s.z += v.z; s.w += v.w;
    }
    h4[t] = s;
}

// ------------- kernel 3: out[o][g] = 0.25 * sum_n (sum_f h[n][o][f]*W[n][f][g] + b[n][g]) -------------
__global__ __launch_bounds__(256) void k_out(const float* __restrict__ h,
                                             const float* __restrict__ Ws,
                                             const float* __restrict__ bs,
                                             float* __restrict__ out) {
    __shared__ float Wsm[N_ENS * 16 * 16];
    __shared__ float bsm[N_ENS * 16];
    int tid = threadIdx.x;
#pragma unroll
    for (int r = 0; r < 4; ++r) Wsm[tid + 256 * r] = Ws[tid + 256 * r];
    if (tid < 64) bsm[tid] = bs[tid];
    __syncthreads();

    int idx = blockIdx.x * 256 + tid;   // 0..65535
    int o = idx >> 4;
    int gg = idx & 15;
    float s = 0.0f;
#pragma unroll
    for (int n = 0; n < N_ENS; ++n) {
        const float* hr = h + ((size_t)(n * N_OUT + o) << 4);
        float t = 0.0f;
#pragma unroll
        for (int f = 0; f < 16; ++f)
            t = fmaf(hr[f], Wsm[n * 256 + f * 16 + gg], t);
        s += t + bsm[n * 16 + gg];
    }
    out[idx] = 0.25f * s;
}

extern "C" void kernel_launch(void* const* d_in, const int* in_sizes, int n_in,
                              void* d_out, int out_size, void* d_ws, size_t ws_size,
                              hipStream_t stream) {
    const float* x  = (const float*)d_in[0];   // [1, 16384, 16]
    const float* As = (const float*)d_in[1];   // [4, 4096, 16384]
    const float* Ws = (const float*)d_in[2];   // [4, 16, 16]
    const float* bs = (const float*)d_in[3];   // [4, 16]
    float* out = (float*)d_out;                // [1, 4096, 16]

    float* hp = (float*)d_ws;                                       // 32 MB: [32][16384][16]
    float* h  = (float*)((char*)d_ws + (size_t)32 * 1024 * 1024);   // 1 MB: [16384][16]
    float* xT = (float*)((char*)d_ws + (size_t)33 * 1024 * 1024);   // 1 MB: [16][16384]

    // hp/h/xT fully overwritten every call -> no memset needed despite 0xAA poison.
    k_transpose<<<(N_IN * 16) / 256, 256, 0, stream>>>(x, xT);
    k_main<<<64 * GSPLIT, 256, 0, stream>>>(As, xT, hp);
    k_hsum<<<(ROWS * 16 / 4) / 256, 256, 0, stream>>>((const float4*)hp, (float4*)h);
    k_out<<<(N_OUT * 16) / 256, 256, 0, stream>>>(h, Ws, bs, out);
}

// Round 6
// 2331.246 us; speedup vs baseline: 1.0100x; 1.0100x over previous
//
#include <hip/hip_runtime.h>

// RandomMFGL: out[o][g] = (1/4) * sum_n [ (A[n] @ x) @ W[n] + b[n] ]
// A: [4][4096][16384] fp32 = 1.07 GB streamed once -> HBM-bound, floor ~175us.
//
// R6 = R5's layout with the scratch bug removed. R5 post-mortem: lambda took
// float4* into ab[2][4] -> SROA defeated -> ping-pong buffers lived in SCRATCH
// (WRITE_SIZE 985 MB vs 32 MB ideal, FETCH 2.5 GB vs 1.07). Fix: named float4
// registers + macros with compile-time step indices; pass body fully unrolled
// so buffer parity is static (no copies, no address-taken arrays).
//
// Layout (measured 0 bank conflicts in R5):
//  - 4 lanes per row (p=lane&3 owns 16B of each 64B step), 16 rows/wave ->
//    each A-load inst covers 16 dense 64B lines (1 KB unique, zero dup).
//  - x pre-transposed xT[16][N_IN]; block stages [16][512]=32 KB LDS once,
//    4 row-passes (256 rows) amortize it. x reads: ds_read_b128, 4 distinct
//    addrs x 16-way broadcast, conflict-free.
//  - Per 1 KB A per wave: 1 VMEM + 16 DS + 64 FMA -> VALU ~31%, HBM saturated.
//  - Split-K=32 partials, butterfly-reduce over the 4 p-lanes, k_hsum + k_out.

#define N_ENS 4
#define N_OUT 4096
#define N_IN  16384
#define ROWS  (N_ENS * N_OUT)      // 16384 rows (row = n*4096 + o)
#define GSPLIT 32                  // split-K factor
#define ICHUNK (N_IN / GSPLIT)     // 512 i per block
#define NPASS 4                    // row-groups of 64 rows per block

// ------------- kernel 0: transpose x [16384][16] -> xT [16][16384] -------------
__global__ __launch_bounds__(256) void k_transpose(const float* __restrict__ x,
                                                   float* __restrict__ xT) {
    int idx = blockIdx.x * 256 + threadIdx.x;   // 0 .. 262143
    int i = idx >> 4;
    int f = idx & 15;
    xT[(size_t)f * N_IN + i] = x[idx];
}

// load batch (PN, SN): 4 dense float4s of this lane's 16B-lane within 64B steps
#define PREF(B0, B1, B2, B3, PN, SN) do {                                   \
    const float* ap_ = Abase + (size_t)(PN) * 64 * N_IN + (SN) * 64;        \
    B0 = *(const float4*)(ap_);                                             \
    B1 = *(const float4*)(ap_ + 16);                                        \
    B2 = *(const float4*)(ap_ + 32);                                        \
    B3 = *(const float4*)(ap_ + 48);                                        \
} while (0)

#define COMP1(BV, XW) do {                                                  \
    _Pragma("unroll")                                                       \
    for (int f = 0; f < 16; ++f) {                                          \
        float4 xv = *(const float4*)&xs[f * ICHUNK + (XW)];                 \
        acc[f] = fmaf(BV.x, xv.x, acc[f]);                                  \
        acc[f] = fmaf(BV.y, xv.y, acc[f]);                                  \
        acc[f] = fmaf(BV.z, xv.z, acc[f]);                                  \
        acc[f] = fmaf(BV.w, xv.w, acc[f]);                                  \
    }                                                                       \
} while (0)

#define COMP(B0, B1, B2, B3, SN) do {                                       \
    COMP1(B0, (SN) * 64 + 0 * 16 + p4);                                     \
    COMP1(B1, (SN) * 64 + 1 * 16 + p4);                                     \
    COMP1(B2, (SN) * 64 + 2 * 16 + p4);                                     \
    COMP1(B3, (SN) * 64 + 3 * 16 + p4);                                     \
} while (0)

// ------------- kernel 1: hp[split][row][f] = sum_{i in chunk} A[row][i] * x[i][f] -------------
__global__ __launch_bounds__(256, 4) void k_main(const float* __restrict__ A,
                                                 const float* __restrict__ xT,
                                                 float* __restrict__ hp) {
    __shared__ float xs[16 * ICHUNK];            // 32 KB: xs[f][i'] = xT[f][i0+i']

    const int split  = blockIdx.x & (GSPLIT - 1);
    const int rowblk = blockIdx.x >> 5;          // 0..63 (256 rows each)
    const int tid = threadIdx.x;
    const int i0  = split * ICHUNK;

    // ---- stage xT chunk [16][512] into LDS: coalesced global, contiguous LDS ----
#pragma unroll
    for (int j = 0; j < 8; ++j) {
        int k  = tid + 256 * j;                  // float4 id, 2048 total
        int f  = k >> 7;                         // 128 float4 per f-row
        int iw = k & 127;
        float4 v = *(const float4*)(xT + (size_t)f * N_IN + i0 + iw * 4);
        *(float4*)&xs[f * ICHUNK + iw * 4] = v;
    }
    __syncthreads();

    const int wave = tid >> 6;
    const int lane = tid & 63;
    const int r    = lane >> 2;                  // 16 rows per wave
    const int p    = lane & 3;                   // 16B quad within row's 64B step
    const int p4   = p << 2;
    const int rowsub = rowblk * 256 + wave * 16 + r;   // + pass*64

    const float* Abase = A + (size_t)rowsub * N_IN + i0 + p4;

    float acc[16];
    float4 c0, c1, c2, c3;   // ping
    float4 n0, n1, n2, n3;   // pong

    PREF(c0, c1, c2, c3, 0, 0);

    for (int pass = 0; pass < NPASS; ++pass) {
#pragma unroll
        for (int f = 0; f < 16; ++f) acc[f] = 0.0f;

        PREF(n0, n1, n2, n3, pass, 1);  COMP(c0, c1, c2, c3, 0);
        PREF(c0, c1, c2, c3, pass, 2);  COMP(n0, n1, n2, n3, 1);
        PREF(n0, n1, n2, n3, pass, 3);  COMP(c0, c1, c2, c3, 2);
        PREF(c0, c1, c2, c3, pass, 4);  COMP(n0, n1, n2, n3, 3);
        PREF(n0, n1, n2, n3, pass, 5);  COMP(c0, c1, c2, c3, 4);
        PREF(c0, c1, c2, c3, pass, 6);  COMP(n0, n1, n2, n3, 5);
        PREF(n0, n1, n2, n3, pass, 7);  COMP(c0, c1, c2, c3, 6);
        {
            int pn = (pass + 1 < NPASS) ? pass + 1 : pass;  // clamp: harmless reload
            PREF(c0, c1, c2, c3, pn, 0);
        }
        COMP(n0, n1, n2, n3, 7);

        // reduce over the 4 p-lanes sharing each row (butterfly keeps lanes valid)
#pragma unroll
        for (int f = 0; f < 16; ++f) {
            acc[f] += __shfl_xor(acc[f], 1, 64);
            acc[f] += __shfl_xor(acc[f], 2, 64);
        }
        float4 v;
        if      (p == 0) v = make_float4(acc[0],  acc[1],  acc[2],  acc[3]);
        else if (p == 1) v = make_float4(acc[4],  acc[5],  acc[6],  acc[7]);
        else if (p == 2) v = make_float4(acc[8],  acc[9],  acc[10], acc[11]);
        else             v = make_float4(acc[12], acc[13], acc[14], acc[15]);
        int row = rowsub + pass * 64;
        // wave writes 16 rows x 64 B contiguous -> dense 1 KB segments
        *(float4*)(hp + (((size_t)split * ROWS + row) << 4) + p4) = v;
    }
}

// ------------- kernel 2: h[row][f] = sum_split hp[split][row][f] (float4) -------------
__global__ __launch_bounds__(256) void k_hsum(const float4* __restrict__ hp4,
                                              float4* __restrict__ h4) {
    int t = blockIdx.x * 256 + threadIdx.x;      // 0 .. 65535 float4s
    float4 s = make_float4(0.f, 0.f, 0.f, 0.f);
#pragma unroll
    for (int sp = 0; sp < GSPLIT; ++sp) {
        float4 v = hp4[(size_t)sp * (ROWS * 4) + t];
        s.x += v.x; s.y += v.y; s.z += v.z; s.w += v.w;
    }
    h4[t] = s;
}

// ------------- kernel 3: out[o][g] = 0.25 * sum_n (sum_f h[n][o][f]*W[n][f][g] + b[n][g]) -------------
__global__ __launch_bounds__(256) void k_out(const float* __restrict__ h,
                                             const float* __restrict__ Ws,
                                             const float* __restrict__ bs,
                                             float* __restrict__ out) {
    __shared__ float Wsm[N_ENS * 16 * 16];
    __shared__ float bsm[N_ENS * 16];
    int tid = threadIdx.x;
#pragma unroll
    for (int r = 0; r < 4; ++r) Wsm[tid + 256 * r] = Ws[tid + 256 * r];
    if (tid < 64) bsm[tid] = bs[tid];
    __syncthreads();

    int idx = blockIdx.x * 256 + tid;   // 0..65535
    int o = idx >> 4;
    int gg = idx & 15;
    float s = 0.0f;
#pragma unroll
    for (int n = 0; n < N_ENS; ++n) {
        const float* hr = h + ((size_t)(n * N_OUT + o) << 4);
        float t = 0.0f;
#pragma unroll
        for (int f = 0; f < 16; ++f)
            t = fmaf(hr[f], Wsm[n * 256 + f * 16 + gg], t);
        s += t + bsm[n * 16 + gg];
    }
    out[idx] = 0.25f * s;
}

extern "C" void kernel_launch(void* const* d_in, const int* in_sizes, int n_in,
                              void* d_out, int out_size, void* d_ws, size_t ws_size,
                              hipStream_t stream) {
    const float* x  = (const float*)d_in[0];   // [1, 16384, 16]
    const float* As = (const float*)d_in[1];   // [4, 4096, 16384]
    const float* Ws = (const float*)d_in[2];   // [4, 16, 16]
    const float* bs = (const float*)d_in[3];   // [4, 16]
    float* out = (float*)d_out;                // [1, 4096, 16]

    float* hp = (float*)d_ws;                                       // 32 MB: [32][16384][16]
    float* h  = (float*)((char*)d_ws + (size_t)32 * 1024 * 1024);   // 1 MB: [16384][16]
    float* xT = (float*)((char*)d_ws + (size_t)33 * 1024 * 1024);   // 1 MB: [16][16384]

    // hp/h/xT fully overwritten every call -> no memset needed despite 0xAA poison.
    k_transpose<<<(N_IN * 16) / 256, 256, 0, stream>>>(x, xT);
    k_main<<<64 * GSPLIT, 256, 0, stream>>>(As, xT, hp);
    k_hsum<<<(ROWS * 16 / 4) / 256, 256, 0, stream>>>((const float4*)hp, (float4*)h);
    k_out<<<(N_OUT * 16) / 256, 256, 0, stream>>>(h, Ws, bs, out);
}